// Round 1
// baseline (384.713 us; speedup 1.0000x reference)
//
#include <hip/hip_runtime.h>

#define D_MODEL 1024
#define TSEQ    4096
#define BATCH   4
#define MROWS   (BATCH * TSEQ)   // 16384
#define KDIM    1024
#define NDIM    1024
#define EPSV    1e-6f

typedef __attribute__((ext_vector_type(8))) short short8;
typedef __attribute__((ext_vector_type(4))) float floatx4;

__device__ inline unsigned short f2bf(float f) {
  unsigned u = __float_as_uint(f);
  unsigned r = (u + 0x7FFFu + ((u >> 16) & 1u)) >> 16;  // RNE
  return (unsigned short)r;
}
__device__ inline float bf2f(unsigned short h) {
  return __uint_as_float(((unsigned)h) << 16);
}
__device__ inline float phi_f(float x) { return x > 0.f ? x + 1.f : __expf(x); }

// ---------------- fp32 -> bf16 convert ----------------
__global__ void cvt_kernel(const float* __restrict__ in,
                           unsigned short* __restrict__ out, int n4) {
  int i = blockIdx.x * blockDim.x + threadIdx.x;
  if (i < n4) {
    float4 f = ((const float4*)in)[i];
    ushort4 o;
    o.x = f2bf(f.x); o.y = f2bf(f.y); o.z = f2bf(f.z); o.w = f2bf(f.w);
    ((ushort4*)out)[i] = o;
  }
}

__global__ void zero_kernel(float* __restrict__ p, int n) {
  int i = blockIdx.x * blockDim.x + threadIdx.x;
  if (i < n) p[i] = 0.f;
}

// ---------------- bf16 GEMM: O = A @ W^T  (A:[M,K] K-major, W:[N,K] K-major) ----
// m97 recipe: 128x128 tile, BK=32, 4 waves (2x2 of 64x64), 16x16x32 bf16 MFMA,
// global_load_lds width=16 staging (wave-uniform base + lane*16 => no LDS pad).
#define BM 128
#define BN 128
#define BK 32

__global__ __launch_bounds__(256) void gemm4_kernel(
    const unsigned short* __restrict__ A,
    const unsigned short* __restrict__ W0, const unsigned short* __restrict__ W1,
    const unsigned short* __restrict__ W2, const unsigned short* __restrict__ W3,
    unsigned short* __restrict__ O0, unsigned short* __restrict__ O1,
    unsigned short* __restrict__ O2, unsigned short* __restrict__ O3)
{
  const int z = blockIdx.z;
  const unsigned short* __restrict__ W = (z == 0) ? W0 : (z == 1) ? W1 : (z == 2) ? W2 : W3;
  unsigned short* __restrict__ O = (z == 0) ? O0 : (z == 1) ? O1 : (z == 2) ? O2 : O3;

  const int bn = blockIdx.x;   // 0..7
  const int bm = blockIdx.y;   // 0..127

  __shared__ __align__(16) unsigned short As[BM * BK];
  __shared__ __align__(16) unsigned short Bs[BN * BK];

  const int tid  = threadIdx.x;
  const int lane = tid & 63;
  const int w    = tid >> 6;          // wave 0..3
  const int wr   = (w >> 1) * 64;     // wave row offset in tile
  const int wc   = (w & 1) * 64;      // wave col offset in tile

  floatx4 acc[4][4];
#pragma unroll
  for (int i = 0; i < 4; i++)
#pragma unroll
    for (int j = 0; j < 4; j++) { floatx4 zz = {0.f, 0.f, 0.f, 0.f}; acc[i][j] = zz; }

  const unsigned short* Ablk = A + (size_t)bm * BM * KDIM;
  const unsigned short* Bblk = W + (size_t)bn * BN * KDIM;

  const int la = lane & 15;           // m/n within 16-tile
  const int lk = (lane >> 4) * 8;     // k element offset

  for (int kt = 0; kt < KDIM; kt += BK) {
    __syncthreads();   // previous tile fully consumed
#pragma unroll
    for (int c = 0; c < 2; c++) {
      int f   = tid + c * 256;        // 0..511, 16B chunk id
      int row = f >> 2;               // 0..127
      int col = (f & 3) * 8;          // 0/8/16/24 elements
      __builtin_amdgcn_global_load_lds(
          (const __attribute__((address_space(1))) void*)(Ablk + (size_t)row * KDIM + kt + col),
          (__attribute__((address_space(3))) void*)(As + (size_t)f * 8), 16, 0, 0);
      __builtin_amdgcn_global_load_lds(
          (const __attribute__((address_space(1))) void*)(Bblk + (size_t)row * KDIM + kt + col),
          (__attribute__((address_space(3))) void*)(Bs + (size_t)f * 8), 16, 0, 0);
    }
    __syncthreads();   // drains vmcnt -> tiles visible

    short8 af[4], bfg[4];
#pragma unroll
    for (int i = 0; i < 4; i++) {
      af[i]  = *(const short8*)&As[(wr + i * 16 + la) * BK + lk];
      bfg[i] = *(const short8*)&Bs[(wc + i * 16 + la) * BK + lk];
    }
#pragma unroll
    for (int i = 0; i < 4; i++)
#pragma unroll
      for (int j = 0; j < 4; j++)
        acc[i][j] = __builtin_amdgcn_mfma_f32_16x16x32_bf16(af[i], bfg[j], acc[i][j], 0, 0, 0);
  }

  // C/D layout (m89-verified): col = lane&15, row = (lane>>4)*4 + r
  const int ro = (lane >> 4) * 4;
  const int co = lane & 15;
#pragma unroll
  for (int i = 0; i < 4; i++) {
#pragma unroll
    for (int j = 0; j < 4; j++) {
      int col = bn * BN + wc + j * 16 + co;
#pragma unroll
      for (int r = 0; r < 4; r++) {
        int row = bm * BM + wr + i * 16 + ro + r;
        O[(size_t)row * NDIM + col] = f2bf(acc[i][j][r]);
      }
    }
  }
}

// ---------------- k_sum / kv_sum reduction over T ----------------
// k_sum[b,n] = sum_t phi(k_lin[b,t,n]);  kv_sum[b,n] = sum_t phi(k_lin)*v
__global__ __launch_bounds__(256) void reduce_kv_kernel(
    const unsigned short* __restrict__ Klin, const unsigned short* __restrict__ V,
    float* __restrict__ ksum, float* __restrict__ kvsum)
{
  const int b  = blockIdx.y;
  const int t0 = blockIdx.x * 64;
  const int n4 = threadIdx.x * 4;
  float sk[4] = {0.f, 0.f, 0.f, 0.f};
  float sv[4] = {0.f, 0.f, 0.f, 0.f};
  const unsigned short* kp = Klin + ((size_t)b * TSEQ + t0) * D_MODEL + n4;
  const unsigned short* vp = V    + ((size_t)b * TSEQ + t0) * D_MODEL + n4;
  for (int t = 0; t < 64; t++) {
    ushort4 ku = *(const ushort4*)(kp + (size_t)t * D_MODEL);
    ushort4 vu = *(const ushort4*)(vp + (size_t)t * D_MODEL);
    float k0 = phi_f(bf2f(ku.x)), k1 = phi_f(bf2f(ku.y)),
          k2 = phi_f(bf2f(ku.z)), k3 = phi_f(bf2f(ku.w));
    sk[0] += k0; sk[1] += k1; sk[2] += k2; sk[3] += k3;
    sv[0] += k0 * bf2f(vu.x); sv[1] += k1 * bf2f(vu.y);
    sv[2] += k2 * bf2f(vu.z); sv[3] += k3 * bf2f(vu.w);
  }
  float* ks = ksum  + (size_t)b * D_MODEL + n4;
  float* vs = kvsum + (size_t)b * D_MODEL + n4;
#pragma unroll
  for (int i = 0; i < 4; i++) { atomicAdd(ks + i, sk[i]); atomicAdd(vs + i, sv[i]); }
}

// ---------------- finalize: s/z per head, gate, blend ----------------
__global__ __launch_bounds__(256) void finalize_kernel(
    const unsigned short* __restrict__ Qlin, const unsigned short* __restrict__ Glin,
    const float* __restrict__ x, const float* __restrict__ bg,
    const float* __restrict__ ksum, const float* __restrict__ kvsum,
    float* __restrict__ out)
{
  const int row = blockIdx.x;          // 0..16383
  const int b   = row >> 12;           // /TSEQ
  const int tid = threadIdx.x;
  const int e   = tid * 4;             // element offset in row (same head for all 4)

  ushort4 qu  = *(const ushort4*)(Qlin + (size_t)row * D_MODEL + e);
  ushort4 gu  = *(const ushort4*)(Glin + (size_t)row * D_MODEL + e);
  float4  xv  = *(const float4*)(x    + (size_t)row * D_MODEL + e);
  float4  bgv = *(const float4*)(bg + e);
  float4  ks  = *(const float4*)(ksum  + (size_t)b * D_MODEL + e);
  float4  kv  = *(const float4*)(kvsum + (size_t)b * D_MODEL + e);

  float q0 = phi_f(bf2f(qu.x)), q1 = phi_f(bf2f(qu.y)),
        q2 = phi_f(bf2f(qu.z)), q3 = phi_f(bf2f(qu.w));
  float s  = q0 * kv.x + q1 * kv.y + q2 * kv.z + q3 * kv.w;
  float zz = q0 * ks.x + q1 * ks.y + q2 * ks.z + q3 * ks.w;
#pragma unroll
  for (int m = 1; m < 16; m <<= 1) {   // 16 lanes = one head (64 dims / 4 per lane)
    s  += __shfl_xor(s, m, 64);
    zz += __shfl_xor(zz, m, 64);
  }
  float o = s / (zz + EPSV);

  float g0 = 1.f / (1.f + __expf(-(bf2f(gu.x) + bgv.x)));
  float g1 = 1.f / (1.f + __expf(-(bf2f(gu.y) + bgv.y)));
  float g2 = 1.f / (1.f + __expf(-(bf2f(gu.z) + bgv.z)));
  float g3 = 1.f / (1.f + __expf(-(bf2f(gu.w) + bgv.w)));

  float4 r;
  r.x = g0 * o + (1.f - g0) * xv.x;
  r.y = g1 * o + (1.f - g1) * xv.y;
  r.z = g2 * o + (1.f - g2) * xv.z;
  r.w = g3 * o + (1.f - g3) * xv.w;
  *(float4*)(out + (size_t)row * D_MODEL + e) = r;
}

extern "C" void kernel_launch(void* const* d_in, const int* in_sizes, int n_in,
                              void* d_out, int out_size, void* d_ws, size_t ws_size,
                              hipStream_t stream) {
  (void)in_sizes; (void)n_in; (void)out_size; (void)ws_size;
  const float* x  = (const float*)d_in[0];
  const float* Wq = (const float*)d_in[1];
  const float* Wk = (const float*)d_in[2];
  const float* Wv = (const float*)d_in[3];
  /* d_in[4] = Wo — unused by the reference */
  const float* Wg = (const float*)d_in[5];
  const float* bg = (const float*)d_in[6];
  float* out = (float*)d_out;

  char* ws = (char*)d_ws;
  const size_t xel = (size_t)MROWS * D_MODEL;      // 16,777,216
  const size_t wel = (size_t)NDIM * KDIM;          // 1,048,576
  unsigned short* xbf  = (unsigned short*)ws; ws += xel * 2;
  unsigned short* wqb  = (unsigned short*)ws; ws += wel * 2;
  unsigned short* wkb  = (unsigned short*)ws; ws += wel * 2;
  unsigned short* wvb  = (unsigned short*)ws; ws += wel * 2;
  unsigned short* wgb  = (unsigned short*)ws; ws += wel * 2;
  unsigned short* qlin = (unsigned short*)ws; ws += xel * 2;
  unsigned short* klin = (unsigned short*)ws; ws += xel * 2;
  unsigned short* vbf  = (unsigned short*)ws; ws += xel * 2;
  unsigned short* glin = (unsigned short*)ws; ws += xel * 2;
  float* ksum  = (float*)ws; ws += (size_t)BATCH * D_MODEL * 4;
  float* kvsum = (float*)ws; ws += (size_t)BATCH * D_MODEL * 4;

  // 1) converts
  cvt_kernel<<<(int)(xel / 4 / 256), 256, 0, stream>>>(x, xbf, (int)(xel / 4));
  cvt_kernel<<<(int)(wel / 4 / 256), 256, 0, stream>>>(Wq, wqb, (int)(wel / 4));
  cvt_kernel<<<(int)(wel / 4 / 256), 256, 0, stream>>>(Wk, wkb, (int)(wel / 4));
  cvt_kernel<<<(int)(wel / 4 / 256), 256, 0, stream>>>(Wv, wvb, (int)(wel / 4));
  cvt_kernel<<<(int)(wel / 4 / 256), 256, 0, stream>>>(Wg, wgb, (int)(wel / 4));

  // 2) four GEMMs in one launch (z selects weight/output)
  dim3 ggrid(NDIM / BN, MROWS / BM, 4);
  gemm4_kernel<<<ggrid, 256, 0, stream>>>(xbf, wqb, wkb, wvb, wgb, qlin, klin, vbf, glin);

  // 3) k_sum / kv_sum
  zero_kernel<<<(2 * BATCH * D_MODEL) / 256, 256, 0, stream>>>(ksum, 2 * BATCH * D_MODEL);
  dim3 rgrid(TSEQ / 64, BATCH);
  reduce_kv_kernel<<<rgrid, 256, 0, stream>>>(klin, vbf, ksum, kvsum);

  // 4) finalize
  finalize_kernel<<<MROWS, 256, 0, stream>>>(qlin, glin, x, bg, ksum, kvsum, out);
}

// Round 2
// 362.176 us; speedup vs baseline: 1.0622x; 1.0622x over previous
//
#include <hip/hip_runtime.h>

#define D_MODEL 1024
#define TSEQ    4096
#define BATCH   4
#define MROWS   (BATCH * TSEQ)   // 16384
#define KDIM    1024
#define NDIM    1024
#define EPSV    1e-6f

typedef __attribute__((ext_vector_type(8))) short short8;
typedef __attribute__((ext_vector_type(4))) float floatx4;

__device__ inline unsigned short f2bf(float f) {
  unsigned u = __float_as_uint(f);
  unsigned r = (u + 0x7FFFu + ((u >> 16) & 1u)) >> 16;  // RNE
  return (unsigned short)r;
}
__device__ inline float bf2f(unsigned short h) {
  return __uint_as_float(((unsigned)h) << 16);
}
__device__ inline float phi_f(float x) { return x > 0.f ? x + 1.f : __expf(x); }

// ---------------- fused prep: fp32->bf16 (x + 4 weights) + zero ksum/kvsum ----
#define NX4 4194304   // x float4 count
#define NW4 262144    // one weight float4 count
#define NZ4 2048      // ksum+kvsum float4 count (8192 floats)

__global__ __launch_bounds__(256) void prep_kernel(
    const float* __restrict__ x,  const float* __restrict__ wq,
    const float* __restrict__ wk, const float* __restrict__ wv,
    const float* __restrict__ wg,
    unsigned short* __restrict__ xb,  unsigned short* __restrict__ wqb,
    unsigned short* __restrict__ wkb, unsigned short* __restrict__ wvb,
    unsigned short* __restrict__ wgb, float* __restrict__ zbase)
{
  long i = (long)blockIdx.x * 256 + threadIdx.x;
  const float* src; unsigned short* dst; long j = i;
  if (j < NX4) { src = x; dst = xb; }
  else {
    j -= NX4;
    if (j < NW4) { src = wq; dst = wqb; }
    else { j -= NW4;
      if (j < NW4) { src = wk; dst = wkb; }
      else { j -= NW4;
        if (j < NW4) { src = wv; dst = wvb; }
        else { j -= NW4;
          if (j < NW4) { src = wg; dst = wgb; }
          else { j -= NW4;
            if (j < NZ4) { float4 zz = {0.f,0.f,0.f,0.f}; ((float4*)zbase)[j] = zz; }
            return;
          }
        }
      }
    }
  }
  float4 f = ((const float4*)src)[j];
  ushort4 o;
  o.x = f2bf(f.x); o.y = f2bf(f.y); o.z = f2bf(f.z); o.w = f2bf(f.w);
  ((ushort4*)dst)[j] = o;
}

// ---------------- paired GEMM: O{0,1} = A @ W{0,1}^T, 128x64 per matrix ------
// z=0: (Wq,Wg) -> write qlin, glin (bf16, vectorized via LDS transpose)
// z=1: (Wk,Wv) -> fused column reduction: ksum += phi(k), kvsum += phi(k)*v
#define BM  128
#define BNH 64
#define BK  32
#define LSP 68   // f32 epilogue row pitch (64 + 4 pad: 2-way banks on write)

__global__ __launch_bounds__(256) void gemm_pair_kernel(
    const unsigned short* __restrict__ A,
    const unsigned short* __restrict__ Wq, const unsigned short* __restrict__ Wg,
    const unsigned short* __restrict__ Wk, const unsigned short* __restrict__ Wv,
    unsigned short* __restrict__ Oq, unsigned short* __restrict__ Og,
    float* __restrict__ ksum, float* __restrict__ kvsum)
{
  const int z  = blockIdx.z;                 // 0: q/g, 1: k/v
  const unsigned short* __restrict__ W0 = z ? Wk : Wq;
  const unsigned short* __restrict__ W1 = z ? Wv : Wg;

  const int bn = blockIdx.x;   // 0..15
  const int bm = blockIdx.y;   // 0..127

  __shared__ __align__(16) unsigned char smem[17408];
  unsigned short* As  = (unsigned short*)smem;      // 128x32
  unsigned short* Bs0 = As + BM * BK;               // 64x32
  unsigned short* Bs1 = Bs0 + BNH * BK;             // 64x32
  float* Ls = (float*)smem;                         // epilogue: [2][32][LSP]

  const int tid   = threadIdx.x;
  const int lane  = tid & 63;
  const int w     = tid >> 6;
  const int mat   = w & 1;      // which output matrix this wave computes
  const int rhalf = w >> 1;     // row half (0: rows 0-63, 1: rows 64-127)

  floatx4 acc[4][4];
#pragma unroll
  for (int i = 0; i < 4; i++)
#pragma unroll
    for (int j = 0; j < 4; j++) { floatx4 zz = {0.f,0.f,0.f,0.f}; acc[i][j] = zz; }

  const unsigned short* Ablk = A + (size_t)bm * BM * KDIM;
  const unsigned short* B0blk = W0 + (size_t)bn * BNH * KDIM;
  const unsigned short* B1blk = W1 + (size_t)bn * BNH * KDIM;

  const int la = lane & 15;
  const int lk = (lane >> 4) * 8;
  const unsigned short* Bsm = mat ? Bs1 : Bs0;

  for (int kt = 0; kt < KDIM; kt += BK) {
    __syncthreads();
    {
      // A: 512 chunks of 16B; thread loads chunks tid and tid+256
#pragma unroll
      for (int c = 0; c < 2; c++) {
        int f   = tid + c * 256;
        int row = f >> 2;
        int col = (f & 3) * 8;
        __builtin_amdgcn_global_load_lds(
            (const __attribute__((address_space(1))) void*)(Ablk + (size_t)row * KDIM + kt + col),
            (__attribute__((address_space(3))) void*)(As + (size_t)f * 8), 16, 0, 0);
      }
      // B0/B1: 256 chunks each; thread loads chunk tid of each
      int row = tid >> 2;
      int col = (tid & 3) * 8;
      __builtin_amdgcn_global_load_lds(
          (const __attribute__((address_space(1))) void*)(B0blk + (size_t)row * KDIM + kt + col),
          (__attribute__((address_space(3))) void*)(Bs0 + (size_t)tid * 8), 16, 0, 0);
      __builtin_amdgcn_global_load_lds(
          (const __attribute__((address_space(1))) void*)(B1blk + (size_t)row * KDIM + kt + col),
          (__attribute__((address_space(3))) void*)(Bs1 + (size_t)tid * 8), 16, 0, 0);
    }
    __syncthreads();

    short8 af[4], bfg[4];
#pragma unroll
    for (int i = 0; i < 4; i++) {
      af[i]  = *(const short8*)&As[(rhalf * 64 + i * 16 + la) * BK + lk];
      bfg[i] = *(const short8*)&Bsm[(i * 16 + la) * BK + lk];
    }
#pragma unroll
    for (int i = 0; i < 4; i++)
#pragma unroll
      for (int j = 0; j < 4; j++)
        acc[i][j] = __builtin_amdgcn_mfma_f32_16x16x32_bf16(af[i], bfg[j], acc[i][j], 0, 0, 0);
  }

  // ---- epilogue: 4 passes over row-groups of 32, via LDS ----
  // C/D layout (m89): col = lane&15, row = (lane>>4)*4 + r
  const int ro = (lane >> 4) * 4;
  const int co = lane & 15;
  float ksum_part = 0.f, kv_part = 0.f;

#pragma unroll
  for (int p = 0; p < 4; p++) {
    __syncthreads();   // previous pass consumed / K-loop LDS reads done
    if (rhalf == (p >> 1)) {
      const int ibase = (p & 1) * 2;
#pragma unroll
      for (int ii = 0; ii < 2; ii++) {
#pragma unroll
        for (int j = 0; j < 4; j++) {
#pragma unroll
          for (int r = 0; r < 4; r++) {
            float vv = acc[ibase + ii][j][r];
            if (z == 1 && mat == 0) vv = phi_f(vv);
            int lr = ii * 16 + ro + r;
            Ls[(mat * 32 + lr) * LSP + j * 16 + co] = vv;
          }
        }
      }
    }
    __syncthreads();
    if (z == 0) {
      const int cmat = tid >> 7, cidx = tid & 127;
      unsigned short* __restrict__ O = cmat ? Og : Oq;
      const int col0  = (cidx & 15) * 4;
      const int rbase = cidx >> 4;           // 0..7
#pragma unroll
      for (int s = 0; s < 4; s++) {
        int lr = rbase + 8 * s;              // 0..31
        float4 f = *(const float4*)&Ls[(cmat * 32 + lr) * LSP + col0];
        ushort4 o4;
        o4.x = f2bf(f.x); o4.y = f2bf(f.y); o4.z = f2bf(f.z); o4.w = f2bf(f.w);
        int grow = bm * BM + p * 32 + lr;
        int gcol = bn * BNH + col0;
        *(ushort4*)(O + (size_t)grow * NDIM + gcol) = o4;
      }
    } else {
      const int ccol = tid & 63, crq = tid >> 6;
#pragma unroll
      for (int rr = 0; rr < 8; rr++) {
        int lr = crq * 8 + rr;
        float kk = Ls[lr * LSP + ccol];
        float vv = Ls[(32 + lr) * LSP + ccol];
        ksum_part += kk;
        kv_part   += kk * vv;
      }
    }
  }

  if (z == 1) {
    __syncthreads();
    float* Lr = (float*)smem;          // [2][4][64]
    const int ccol = tid & 63, crq = tid >> 6;
    Lr[crq * 64 + ccol]       = ksum_part;
    Lr[256 + crq * 64 + ccol] = kv_part;
    __syncthreads();
    if (tid < 128) {
      const int qq = tid >> 6, col = tid & 63;
      const float* base = Lr + qq * 256;
      float s4 = base[col] + base[64 + col] + base[128 + col] + base[192 + col];
      const int b = bm >> 5;             // 128 rows per block, 4096 rows per batch
      float* dst = (qq ? kvsum : ksum) + (size_t)b * D_MODEL + bn * BNH + col;
      atomicAdd(dst, s4);
    }
  }
}

// ---------------- finalize: s/z per head, gate, blend ----------------
__global__ __launch_bounds__(256) void finalize_kernel(
    const unsigned short* __restrict__ Qlin, const unsigned short* __restrict__ Glin,
    const float* __restrict__ x, const float* __restrict__ bg,
    const float* __restrict__ ksum, const float* __restrict__ kvsum,
    float* __restrict__ out)
{
  const int row = blockIdx.x;          // 0..16383
  const int b   = row >> 12;
  const int tid = threadIdx.x;
  const int e   = tid * 4;             // 4 dims, same head for all 4

  ushort4 qu  = *(const ushort4*)(Qlin + (size_t)row * D_MODEL + e);
  ushort4 gu  = *(const ushort4*)(Glin + (size_t)row * D_MODEL + e);
  float4  xv  = *(const float4*)(x    + (size_t)row * D_MODEL + e);
  float4  bgv = *(const float4*)(bg + e);
  float4  ks  = *(const float4*)(ksum  + (size_t)b * D_MODEL + e);
  float4  kv  = *(const float4*)(kvsum + (size_t)b * D_MODEL + e);

  float q0 = phi_f(bf2f(qu.x)), q1 = phi_f(bf2f(qu.y)),
        q2 = phi_f(bf2f(qu.z)), q3 = phi_f(bf2f(qu.w));
  float s  = q0 * kv.x + q1 * kv.y + q2 * kv.z + q3 * kv.w;
  float zz = q0 * ks.x + q1 * ks.y + q2 * ks.z + q3 * ks.w;
#pragma unroll
  for (int m = 1; m < 16; m <<= 1) {   // 16 lanes = one head
    s  += __shfl_xor(s, m, 64);
    zz += __shfl_xor(zz, m, 64);
  }
  float o = s / (zz + EPSV);

  float g0 = 1.f / (1.f + __expf(-(bf2f(gu.x) + bgv.x)));
  float g1 = 1.f / (1.f + __expf(-(bf2f(gu.y) + bgv.y)));
  float g2 = 1.f / (1.f + __expf(-(bf2f(gu.z) + bgv.z)));
  float g3 = 1.f / (1.f + __expf(-(bf2f(gu.w) + bgv.w)));

  float4 r;
  r.x = g0 * o + (1.f - g0) * xv.x;
  r.y = g1 * o + (1.f - g1) * xv.y;
  r.z = g2 * o + (1.f - g2) * xv.z;
  r.w = g3 * o + (1.f - g3) * xv.w;
  *(float4*)(out + (size_t)row * D_MODEL + e) = r;
}

extern "C" void kernel_launch(void* const* d_in, const int* in_sizes, int n_in,
                              void* d_out, int out_size, void* d_ws, size_t ws_size,
                              hipStream_t stream) {
  (void)in_sizes; (void)n_in; (void)out_size; (void)ws_size;
  const float* x  = (const float*)d_in[0];
  const float* Wq = (const float*)d_in[1];
  const float* Wk = (const float*)d_in[2];
  const float* Wv = (const float*)d_in[3];
  /* d_in[4] = Wo — unused by the reference */
  const float* Wg = (const float*)d_in[5];
  const float* bg = (const float*)d_in[6];
  float* out = (float*)d_out;

  char* ws = (char*)d_ws;
  const size_t xel = (size_t)MROWS * D_MODEL;
  const size_t wel = (size_t)NDIM * KDIM;
  unsigned short* xbf  = (unsigned short*)ws; ws += xel * 2;
  unsigned short* wqb  = (unsigned short*)ws; ws += wel * 2;
  unsigned short* wkb  = (unsigned short*)ws; ws += wel * 2;
  unsigned short* wvb  = (unsigned short*)ws; ws += wel * 2;
  unsigned short* wgb  = (unsigned short*)ws; ws += wel * 2;
  unsigned short* qlin = (unsigned short*)ws; ws += xel * 2;
  unsigned short* glin = (unsigned short*)ws; ws += xel * 2;
  float* ksum  = (float*)ws; ws += (size_t)BATCH * D_MODEL * 4;   // contiguous with kvsum
  float* kvsum = (float*)ws; ws += (size_t)BATCH * D_MODEL * 4;

  // 1) fused converts + zero (ksum/kvsum are contiguous: zero from ksum base)
  const long total4 = (long)NX4 + 4L * NW4 + NZ4;
  prep_kernel<<<(int)((total4 + 255) / 256), 256, 0, stream>>>(
      x, Wq, Wk, Wv, Wg, xbf, wqb, wkb, wvb, wgb, ksum);

  // 2) paired GEMMs: z=0 (q,g) writes bf16; z=1 (k,v) fused reduction
  dim3 ggrid(NDIM / BNH, MROWS / BM, 2);
  gemm_pair_kernel<<<ggrid, 256, 0, stream>>>(
      xbf, wqb, wgb, wkb, wvb, qlin, glin, ksum, kvsum);

  // 3) finalize
  finalize_kernel<<<MROWS, 256, 0, stream>>>(qlin, glin, x, bg, ksum, kvsum, out);
}

// Round 3
// 296.367 us; speedup vs baseline: 1.2981x; 1.2221x over previous
//
#include <hip/hip_runtime.h>

#define D_MODEL 1024
#define TSEQ    4096
#define BATCH   4
#define MROWS   (BATCH * TSEQ)   // 16384
#define KDIM    1024
#define NDIM    1024
#define EPSV    1e-6f

typedef __attribute__((ext_vector_type(8))) short short8;
typedef __attribute__((ext_vector_type(4))) float floatx4;

__device__ inline unsigned short f2bf(float f) {
  unsigned u = __float_as_uint(f);
  unsigned r = (u + 0x7FFFu + ((u >> 16) & 1u)) >> 16;  // RNE
  return (unsigned short)r;
}
__device__ inline float bf2f(unsigned short h) {
  return __uint_as_float(((unsigned)h) << 16);
}
__device__ inline float phi_f(float x) { return x > 0.f ? x + 1.f : __expf(x); }

// ---------------- fused prep: fp32->bf16 (x + 4 weights) + zero ksum/kvsum ----
#define NX4 4194304   // x float4 count
#define NW4 262144    // one weight float4 count
#define NZ4 2048      // ksum+kvsum float4 count

__global__ __launch_bounds__(256) void prep_kernel(
    const float* __restrict__ x,  const float* __restrict__ wq,
    const float* __restrict__ wk, const float* __restrict__ wv,
    const float* __restrict__ wg,
    unsigned short* __restrict__ xb,  unsigned short* __restrict__ wqb,
    unsigned short* __restrict__ wkb, unsigned short* __restrict__ wvb,
    unsigned short* __restrict__ wgb, float* __restrict__ zbase)
{
  long i = (long)blockIdx.x * 256 + threadIdx.x;
  const float* src; unsigned short* dst; long j = i;
  if (j < NX4) { src = x; dst = xb; }
  else {
    j -= NX4;
    if (j < NW4) { src = wq; dst = wqb; }
    else { j -= NW4;
      if (j < NW4) { src = wk; dst = wkb; }
      else { j -= NW4;
        if (j < NW4) { src = wv; dst = wvb; }
        else { j -= NW4;
          if (j < NW4) { src = wg; dst = wgb; }
          else { j -= NW4;
            if (j < NZ4) { float4 zz = {0.f,0.f,0.f,0.f}; ((float4*)zbase)[j] = zz; }
            return;
          }
        }
      }
    }
  }
  float4 f = ((const float4*)src)[j];
  ushort4 o;
  o.x = f2bf(f.x); o.y = f2bf(f.y); o.z = f2bf(f.z); o.w = f2bf(f.w);
  ((ushort4*)dst)[j] = o;
}

#define BM 128
#define BN 128
#define BK 32

// ---------------- phase 1: k/v GEMM with in-register fused reduction --------
// Each wave computes BOTH k and v 64x64 tiles for the same (rows,cols) region
// (shared A fragments). phi(k) and phi(k)*v are reduced per-lane over its own
// 16 rows, xor-shuffled over row-quads, then atomicAdd'd. k/v never hit HBM.
__global__ __launch_bounds__(256, 2) void gemm_kv_kernel(
    const unsigned short* __restrict__ A,
    const unsigned short* __restrict__ Wk, const unsigned short* __restrict__ Wv,
    float* __restrict__ ksum, float* __restrict__ kvsum)
{
  const int bn = blockIdx.x;   // 0..7
  const int bm = blockIdx.y;   // 0..127

  __shared__ __align__(16) unsigned short As[BM * BK];
  __shared__ __align__(16) unsigned short Bk[BN * BK];
  __shared__ __align__(16) unsigned short Bv[BN * BK];

  const int tid  = threadIdx.x;
  const int lane = tid & 63;
  const int w    = tid >> 6;          // 0..3
  const int wr   = (w >> 1) * 64;
  const int wc   = (w & 1) * 64;

  floatx4 ak[4][4], av[4][4];
#pragma unroll
  for (int i = 0; i < 4; i++)
#pragma unroll
    for (int j = 0; j < 4; j++) {
      floatx4 zz = {0.f,0.f,0.f,0.f}; ak[i][j] = zz; av[i][j] = zz;
    }

  const unsigned short* Ablk  = A  + (size_t)bm * BM * KDIM;
  const unsigned short* Bkblk = Wk + (size_t)bn * BN * KDIM;
  const unsigned short* Bvblk = Wv + (size_t)bn * BN * KDIM;

  const int la = lane & 15;
  const int lk = (lane >> 4) * 8;

  for (int kt = 0; kt < KDIM; kt += BK) {
    __syncthreads();
#pragma unroll
    for (int c = 0; c < 2; c++) {
      int f   = tid + c * 256;        // 0..511
      int row = f >> 2;
      int col = (f & 3) * 8;
      size_t goff = (size_t)row * KDIM + kt + col;
      __builtin_amdgcn_global_load_lds(
          (const __attribute__((address_space(1))) void*)(Ablk + goff),
          (__attribute__((address_space(3))) void*)(As + (size_t)f * 8), 16, 0, 0);
      __builtin_amdgcn_global_load_lds(
          (const __attribute__((address_space(1))) void*)(Bkblk + goff),
          (__attribute__((address_space(3))) void*)(Bk + (size_t)f * 8), 16, 0, 0);
      __builtin_amdgcn_global_load_lds(
          (const __attribute__((address_space(1))) void*)(Bvblk + goff),
          (__attribute__((address_space(3))) void*)(Bv + (size_t)f * 8), 16, 0, 0);
    }
    __syncthreads();

    short8 af[4], bk[4], bv[4];
#pragma unroll
    for (int i = 0; i < 4; i++) {
      af[i] = *(const short8*)&As[(wr + i * 16 + la) * BK + lk];
      bk[i] = *(const short8*)&Bk[(wc + i * 16 + la) * BK + lk];
      bv[i] = *(const short8*)&Bv[(wc + i * 16 + la) * BK + lk];
    }
#pragma unroll
    for (int i = 0; i < 4; i++)
#pragma unroll
      for (int j = 0; j < 4; j++) {
        ak[i][j] = __builtin_amdgcn_mfma_f32_16x16x32_bf16(af[i], bk[j], ak[i][j], 0, 0, 0);
        av[i][j] = __builtin_amdgcn_mfma_f32_16x16x32_bf16(af[i], bv[j], av[i][j], 0, 0, 0);
      }
  }

  // ---- fused column reduction ----
  const int b = bm >> 5;              // 32 bm-blocks per batch
  float kp[4] = {0.f,0.f,0.f,0.f};
  float vp[4] = {0.f,0.f,0.f,0.f};
#pragma unroll
  for (int j = 0; j < 4; j++)
#pragma unroll
    for (int i = 0; i < 4; i++)
#pragma unroll
      for (int r = 0; r < 4; r++) {
        float kk = phi_f(ak[i][j][r]);
        kp[j] += kk;
        vp[j] += kk * av[i][j][r];
      }
  // sum over the 4 row-quads (lane>>4): xor 16, 32
#pragma unroll
  for (int j = 0; j < 4; j++) {
    kp[j] += __shfl_xor(kp[j], 16, 64); kp[j] += __shfl_xor(kp[j], 32, 64);
    vp[j] += __shfl_xor(vp[j], 16, 64); vp[j] += __shfl_xor(vp[j], 32, 64);
  }
  if (lane < 16) {
#pragma unroll
    for (int j = 0; j < 4; j++) {
      int col = bn * BN + wc + j * 16 + lane;
      atomicAdd(ksum  + (size_t)b * D_MODEL + col, kp[j]);
      atomicAdd(kvsum + (size_t)b * D_MODEL + col, vp[j]);
    }
  }
}

// ---------------- phase 2: q/g GEMM with fused finalize ---------------------
// 512 threads: waves 0-3 compute q 128x128, waves 4-7 compute g 128x128.
// A 128-col tile = exactly 2 heads -> s,z fully reducible in-block.
__global__ __launch_bounds__(512) void gemm_qg_kernel(
    const unsigned short* __restrict__ A,
    const unsigned short* __restrict__ Wq, const unsigned short* __restrict__ Wg,
    const float* __restrict__ x, const float* __restrict__ bg,
    const float* __restrict__ ksum, const float* __restrict__ kvsum,
    float* __restrict__ out)
{
  const int bn = blockIdx.x;   // 0..7
  const int bm = blockIdx.y;   // 0..127

  __shared__ __align__(16) unsigned short As[BM * BK];
  __shared__ __align__(16) unsigned short Bq[BN * BK];
  __shared__ __align__(16) unsigned short Bg[BN * BK];
  __shared__ float o_lds[2 * BM];     // [head_local][row_local]

  const int tid  = threadIdx.x;
  const int lane = tid & 63;
  const int w    = tid >> 6;          // 0..7
  const int is_g = w >> 2;
  const int wl   = w & 3;
  const int wr   = (wl >> 1) * 64;
  const int wc   = (wl & 1) * 64;

  floatx4 acc[4][4];
#pragma unroll
  for (int i = 0; i < 4; i++)
#pragma unroll
    for (int j = 0; j < 4; j++) { floatx4 zz = {0.f,0.f,0.f,0.f}; acc[i][j] = zz; }

  const unsigned short* Ablk  = A + (size_t)bm * BM * KDIM;
  const unsigned short* Bqblk = Wq + (size_t)bn * BN * KDIM;
  const unsigned short* Bgblk = Wg + (size_t)bn * BN * KDIM;

  const int la = lane & 15;
  const int lk = (lane >> 4) * 8;
  const unsigned short* Bsm = is_g ? Bg : Bq;

  for (int kt = 0; kt < KDIM; kt += BK) {
    __syncthreads();
    {
      int f   = tid;                  // 0..511
      int row = f >> 2;
      int col = (f & 3) * 8;
      size_t goff = (size_t)row * KDIM + kt + col;
      __builtin_amdgcn_global_load_lds(
          (const __attribute__((address_space(1))) void*)(Ablk + goff),
          (__attribute__((address_space(3))) void*)(As + (size_t)f * 8), 16, 0, 0);
      __builtin_amdgcn_global_load_lds(
          (const __attribute__((address_space(1))) void*)(Bqblk + goff),
          (__attribute__((address_space(3))) void*)(Bq + (size_t)f * 8), 16, 0, 0);
      __builtin_amdgcn_global_load_lds(
          (const __attribute__((address_space(1))) void*)(Bgblk + goff),
          (__attribute__((address_space(3))) void*)(Bg + (size_t)f * 8), 16, 0, 0);
    }
    __syncthreads();

    short8 af[4], bfg[4];
#pragma unroll
    for (int i = 0; i < 4; i++) {
      af[i]  = *(const short8*)&As[(wr + i * 16 + la) * BK + lk];
      bfg[i] = *(const short8*)&Bsm[(wc + i * 16 + la) * BK + lk];
    }
#pragma unroll
    for (int i = 0; i < 4; i++)
#pragma unroll
      for (int j = 0; j < 4; j++)
        acc[i][j] = __builtin_amdgcn_mfma_f32_16x16x32_bf16(af[i], bfg[j], acc[i][j], 0, 0, 0);
  }

  // ---- fused finalize ----
  const int b  = bm >> 5;
  const int ro = (lane >> 4) * 4;
  const int co = lane & 15;
  const int hl = wc >> 6;             // head_local (0/1): wave spans one head

  if (!is_g) {
    float kvv[4], ksv[4];
#pragma unroll
    for (int j = 0; j < 4; j++) {
      int col = bn * BN + wc + j * 16 + co;
      kvv[j] = kvsum[(size_t)b * D_MODEL + col];
      ksv[j] = ksum [(size_t)b * D_MODEL + col];
    }
#pragma unroll
    for (int i = 0; i < 4; i++)
#pragma unroll
      for (int r = 0; r < 4; r++) {
        float s = 0.f, z = 0.f;
#pragma unroll
        for (int j = 0; j < 4; j++) {
          float qq = phi_f(acc[i][j][r]);
          s += qq * kvv[j]; z += qq * ksv[j];
        }
#pragma unroll
        for (int m = 1; m < 16; m <<= 1) {  // sum cols across 16-lane group
          s += __shfl_xor(s, m, 64);
          z += __shfl_xor(z, m, 64);
        }
        if (co == 0) o_lds[hl * BM + wr + i * 16 + ro + r] = s / (z + EPSV);
      }
  }
  __syncthreads();
  if (is_g) {
    float bgv[4];
#pragma unroll
    for (int j = 0; j < 4; j++) bgv[j] = bg[bn * BN + wc + j * 16 + co];
#pragma unroll
    for (int i = 0; i < 4; i++)
#pragma unroll
      for (int r = 0; r < 4; r++) {
        int rowl = wr + i * 16 + ro + r;
        int grow = bm * BM + rowl;
        float ov = o_lds[hl * BM + rowl];
#pragma unroll
        for (int j = 0; j < 4; j++) {
          int gcol = bn * BN + wc + j * 16 + co;
          float gt = 1.f / (1.f + __expf(-(acc[i][j][r] + bgv[j])));
          float xv = x[(size_t)grow * D_MODEL + gcol];
          out[(size_t)grow * D_MODEL + gcol] = gt * ov + (1.f - gt) * xv;
        }
      }
  }
}

extern "C" void kernel_launch(void* const* d_in, const int* in_sizes, int n_in,
                              void* d_out, int out_size, void* d_ws, size_t ws_size,
                              hipStream_t stream) {
  (void)in_sizes; (void)n_in; (void)out_size; (void)ws_size;
  const float* x  = (const float*)d_in[0];
  const float* Wq = (const float*)d_in[1];
  const float* Wk = (const float*)d_in[2];
  const float* Wv = (const float*)d_in[3];
  /* d_in[4] = Wo — unused by the reference */
  const float* Wg = (const float*)d_in[5];
  const float* bg = (const float*)d_in[6];
  float* out = (float*)d_out;

  char* ws = (char*)d_ws;
  const size_t xel = (size_t)MROWS * D_MODEL;
  const size_t wel = (size_t)NDIM * KDIM;
  unsigned short* xbf = (unsigned short*)ws; ws += xel * 2;
  unsigned short* wqb = (unsigned short*)ws; ws += wel * 2;
  unsigned short* wkb = (unsigned short*)ws; ws += wel * 2;
  unsigned short* wvb = (unsigned short*)ws; ws += wel * 2;
  unsigned short* wgb = (unsigned short*)ws; ws += wel * 2;
  float* ksum  = (float*)ws; ws += (size_t)BATCH * D_MODEL * 4;  // contiguous
  float* kvsum = (float*)ws; ws += (size_t)BATCH * D_MODEL * 4;

  // 1) fused converts + zero
  const long total4 = (long)NX4 + 4L * NW4 + NZ4;
  prep_kernel<<<(int)((total4 + 255) / 256), 256, 0, stream>>>(
      x, Wq, Wk, Wv, Wg, xbf, wqb, wkb, wvb, wgb, ksum);

  // 2) phase 1: k/v with fused reduction
  dim3 g1(NDIM / BN, MROWS / BM);
  gemm_kv_kernel<<<g1, 256, 0, stream>>>(xbf, wkb, wvb, ksum, kvsum);

  // 3) phase 2: q/g with fused finalize
  dim3 g2(NDIM / BN, MROWS / BM);
  gemm_qg_kernel<<<g2, 512, 0, stream>>>(xbf, wqb, wgb, x, bg, ksum, kvsum, out);
}